// Round 15
// baseline (121.904 us; speedup 1.0000x reference)
//
#include <hip/hip_runtime.h>
#include <hip/hip_bf16.h>
#include <hip/hip_fp8.h>

#define NNODE 50000
#define MTOT  100000   // 2*NNODE rows
#define NF    256
#define KNB   10

typedef unsigned short u16;
typedef float f32x4 __attribute__((ext_vector_type(4)));
typedef float f32x2 __attribute__((ext_vector_type(2)));
typedef short bf16x8 __attribute__((ext_vector_type(8)));

__device__ __forceinline__ u16 f2bf(float f) {
    unsigned u = __builtin_bit_cast(unsigned, f);
    unsigned r = (u + 0x7fffu + ((u >> 16) & 1u)) >> 16;
    return (u16)r;
}
__device__ __forceinline__ unsigned char f2f8(float f) {
    return (unsigned char)__hip_fp8_e4m3(f).__x;
}
__device__ __forceinline__ float f8tof(unsigned char b) {
    __hip_fp8_e4m3 h;
    h.__x = (__hip_fp8_storage_t)b;
    return (float)h;
}
template <int WORD>
__device__ __forceinline__ f32x2 cvt2_fp8(unsigned v) {
#if __has_builtin(__builtin_amdgcn_cvt_pk_f32_fp8)
    auto c = __builtin_amdgcn_cvt_pk_f32_fp8((int)v, WORD);
    f32x2 r; r.x = c[0]; r.y = c[1];
    return r;
#else
    unsigned s = WORD ? (v >> 16) : v;
    f32x2 r;
    r.x = f8tof((unsigned char)(s & 0xff));
    r.y = f8tof((unsigned char)((s >> 8) & 0xff));
    return r;
#endif
}
template <int WORD>
__device__ __forceinline__ unsigned pk_fp8(float a, float b, unsigned old) {
#if __has_builtin(__builtin_amdgcn_cvt_pk_fp8_f32)
    return (unsigned)__builtin_amdgcn_cvt_pk_fp8_f32(a, b, (int)old, WORD);
#else
    unsigned lo = (unsigned)f2f8(a) | ((unsigned)f2f8(b) << 8);
    return WORD ? ((old & 0x0000ffffu) | (lo << 16)) : ((old & 0xffff0000u) | lo);
#endif
}
__device__ __forceinline__ void gload_lds16(const void* g, void* l) {
    __builtin_amdgcn_global_load_lds(
        (const __attribute__((address_space(1))) unsigned int*)g,
        (__attribute__((address_space(3))) unsigned int*)l, 16, 0, 0);
}

// ---- kernel 1: merged cast.
//  [0,12500): Z -> bf16 Zleft + fp8 Z8
//  [12500,12756): WT bf16 [256 n][256 k] = Wr^T
//  [12756,13012): WT8 fp8 [256 n][256 k] = Wnr^T, 8B-halves of each 16B swapped
//                 when (n>>2)&1 (bank-spread bake for the right-B LDS reads)
__global__ __launch_bounds__(256) void cast_all(const float* __restrict__ Z1,
                                                const float* __restrict__ Z2,
                                                const float* __restrict__ Wr,
                                                const float* __restrict__ Wnr,
                                                u16* __restrict__ Zleft,
                                                unsigned char* __restrict__ Z8,
                                                u16* __restrict__ WT,
                                                unsigned char* __restrict__ WT8) {
    int b = blockIdx.x;
    if (b < 12500) {
        unsigned id = b * 256 + threadIdx.x;
        int m = id >> 5;
        int d = (id & 31) << 3;
        const float* src = (m < NNODE) ? (Z1 + (size_t)m * 256 + d)
                                       : (Z2 + (size_t)(m - NNODE) * 256 + d);
        float4 a = *(const float4*)src;
        float4 bb = *(const float4*)(src + 4);
        uint4 o;
        o.x = (unsigned)f2bf(a.x) | ((unsigned)f2bf(a.y) << 16);
        o.y = (unsigned)f2bf(a.z) | ((unsigned)f2bf(a.w) << 16);
        o.z = (unsigned)f2bf(bb.x) | ((unsigned)f2bf(bb.y) << 16);
        o.w = (unsigned)f2bf(bb.z) | ((unsigned)f2bf(bb.w) << 16);
        *(uint4*)(Zleft + (size_t)m * 256 + d) = o;
        uint2 o8;
        o8.x = (unsigned)f2f8(a.x) | ((unsigned)f2f8(a.y) << 8) |
               ((unsigned)f2f8(a.z) << 16) | ((unsigned)f2f8(a.w) << 24);
        o8.y = (unsigned)f2f8(bb.x) | ((unsigned)f2f8(bb.y) << 8) |
               ((unsigned)f2f8(bb.z) << 16) | ((unsigned)f2f8(bb.w) << 24);
        *(uint2*)(Z8 + (size_t)m * 256 + d) = o8;
    } else if (b < 12756) {
        int id = (b - 12500) * 256 + threadIdx.x;
        int n = id >> 8, k = id & 255;
        WT[n * 256 + k] = f2bf(Wr[(size_t)k * 256 + n]);
    } else {
        int id = (b - 12756) * 256 + threadIdx.x;
        int n = id >> 8, k = id & 255;
        int kb = k ^ (((n >> 2) & 1) << 3);          // bake: swap 8B halves per 16B
        WT8[n * 256 + kb] = f2f8(Wnr[(size_t)k * 256 + n]);
    }
}

// ---- staging: linear LDS dest + inverse-swizzled global source (16B granules)
__device__ __forceinline__ void stageA(const u16* __restrict__ Zl, u16* dst,
                                       int m0, int kt, int t) {
    // [64r][64k] bf16 = 512 granules, 1/thread, XOR row&7 (8 granules/row)
    int row = t >> 3, gd = t & 7;
    int gs = gd ^ (row & 7);
    int grow = m0 + row;
    if (grow >= MTOT) grow = MTOT - 1;
    gload_lds16(Zl + (size_t)grow * 256 + kt + gs * 8, dst + t * 8);
}
__device__ __forceinline__ void stageBl(const u16* __restrict__ WT, u16* dst,
                                        int kt, int t) {
    // [256c][64k] bf16 = 2048 granules, 4/thread, XOR col&7
    #pragma unroll
    for (int rp = 0; rp < 4; ++rp) {
        int c = rp * 512 + t;
        int col = c >> 3, gd = c & 7;
        int gs = gd ^ (col & 7);
        gload_lds16(WT + (size_t)col * 256 + kt + gs * 8, dst + c * 8);
    }
}
__device__ __forceinline__ void stageBr(const unsigned char* __restrict__ WT8,
                                        unsigned char* dst, int ktr, int t) {
    // [256c][64k] fp8 = 1024 granules, 2/thread, XOR col&3 (half-bake in data)
    #pragma unroll
    for (int rp = 0; rp < 2; ++rp) {
        int c = rp * 512 + t;
        int col = c >> 2, gd = c & 3;
        int gs = gd ^ (col & 3);
        gload_lds16(WT8 + (size_t)col * 256 + ktr + gs * 16, dst + c * 16);
    }
}

__device__ __forceinline__ void mfma_left(const u16* sAc, const u16* sBc, int lane,
                                          int wr, int wc, f32x4 (&acc)[2][4]) {
    const int hi = lane >> 4, l15 = lane & 15;
    #pragma unroll
    for (int kk = 0; kk < 64; kk += 32) {
        int g = (kk >> 3) + hi;                     // granule 0..7
        bf16x8 af[2], bfr[4];
        #pragma unroll
        for (int i = 0; i < 2; ++i) {
            int row = wr * 32 + i * 16 + l15;
            af[i] = *(const bf16x8*)((const char*)sAc + row * 128 + ((g ^ (row & 7)) << 4));
        }
        #pragma unroll
        for (int j = 0; j < 4; ++j) {
            int col = wc * 64 + j * 16 + l15;
            bfr[j] = *(const bf16x8*)((const char*)sBc + col * 128 + ((g ^ (col & 7)) << 4));
        }
        #pragma unroll
        for (int i = 0; i < 2; ++i)
            #pragma unroll
            for (int j = 0; j < 4; ++j)
                acc[i][j] = __builtin_amdgcn_mfma_f32_16x16x32_bf16(af[i], bfr[j], acc[i][j], 0, 0, 0);
    }
}
__device__ __forceinline__ void mfma_right(const unsigned char* sZ, const unsigned char* sBc,
                                           int R, int lane, int wr, int wc,
                                           f32x4 (&acc)[2][4]) {
    const int hi = lane >> 4, l15 = lane & 15;
    #pragma unroll
    for (int m = 0; m < 2; ++m) {
        long long az[2], bz[4];
        #pragma unroll
        for (int i = 0; i < 2; ++i) {
            int row = wr * 32 + i * 16 + l15;
            int g8 = R * 8 + m * 4 + hi;            // 8B granule 0..31
            az[i] = *(const long long*)(sZ + row * 256 + ((g8 ^ (row & 7)) << 3));
        }
        #pragma unroll
        for (int j = 0; j < 4; ++j) {
            int col = wc * 64 + j * 16 + l15;
            int G = 2 * m + (hi >> 1);              // 16B granule 0..3
            int hb = ((hi & 1) ^ ((col >> 2) & 1)) << 3;   // un-bake half select
            bz[j] = *(const long long*)(sBc + col * 64 + ((G ^ (col & 3)) << 4) + hb);
        }
        #pragma unroll
        for (int i = 0; i < 2; ++i)
            #pragma unroll
            for (int j = 0; j < 4; ++j)
                acc[i][j] = __builtin_amdgcn_mfma_f32_16x16x32_fp8_fp8(az[i], bz[j], acc[i][j], 0, 0, 0);
    }
}

// ---- consume gather packet of step s: merge even/odd halves -> avg -> fp8 -> sZ.
// Lane layout (matches gather): lanes0-15 row+0/even-k, 16-31 row+1/even-k,
// 32-47 row+0/odd-k, 48-63 row+1/odd-k; lane covers cols (lane&15)*16..+15.
// Partner lane^32 holds same row/cols, other 5 neighbors -> shfl_xor(32) merge.
__device__ __forceinline__ void consume(const uint4 (&gv)[5], unsigned mask, int cnt,
                                        int w, int lane, int s, unsigned char* sZ) {
    f32x2 a[8];
    #pragma unroll
    for (int j = 0; j < 8; ++j) a[j] = f32x2{0.f, 0.f};
    #pragma unroll
    for (int q = 0; q < 5; ++q) {
        float mm = (float)((mask >> q) & 1u);
        f32x2 m2 = {mm, mm};
        a[0] += m2 * cvt2_fp8<0>(gv[q].x); a[1] += m2 * cvt2_fp8<1>(gv[q].x);
        a[2] += m2 * cvt2_fp8<0>(gv[q].y); a[3] += m2 * cvt2_fp8<1>(gv[q].y);
        a[4] += m2 * cvt2_fp8<0>(gv[q].z); a[5] += m2 * cvt2_fp8<1>(gv[q].z);
        a[6] += m2 * cvt2_fp8<0>(gv[q].w); a[7] += m2 * cvt2_fp8<1>(gv[q].w);
    }
    int cfull = cnt + __shfl_xor(cnt, 32, 64);
    #pragma unroll
    for (int j = 0; j < 8; ++j) {
        a[j].x += __shfl_xor(a[j].x, 32, 64);
        a[j].y += __shfl_xor(a[j].y, 32, 64);
    }
    float sc = 1.0f / (float)(cfull > 0 ? cfull : 1);
    unsigned pw[4];
    #pragma unroll
    for (int j = 0; j < 4; ++j) {
        unsigned v = pk_fp8<0>(a[2 * j].x * sc, a[2 * j].y * sc, 0u);
        pw[j] = pk_fp8<1>(a[2 * j + 1].x * sc, a[2 * j + 1].y * sc, v);
    }
    if (lane < 32) {                                  // one writer per row-half
        int rl = w * 8 + s * 2 + ((lane >> 4) & 1);   // local row 0..63
        int m = lane & 15;
        int e = rl & 7;
        *(uint2*)(sZ + rl * 256 + ((( 2 * m    ) ^ e) << 3)) = make_uint2(pw[0], pw[1]);
        *(uint2*)(sZ + rl * 256 + (((2 * m + 1) ^ e) << 3)) = make_uint2(pw[2], pw[3]);
    }
}

// ---- left step S (0..3): pinned issue order + counted vmcnt.
// TWO barriers per step, both load-bearing: the pre-MFMA barrier publishes the
// staged B(S)/A tiles; the TRAILING barrier keeps any wave from staging B(S+1)
// over the single sBL buffer while another wave still MFMA-reads B(S).
// (R13 dropped the trailing barrier -> absmax 36 data race. Do not remove.)
template <int S>
__device__ __forceinline__ void left_step(const u16* __restrict__ Zl,
                                          const u16* __restrict__ WT,
                                          const unsigned char* __restrict__ Z8,
                                          const int* __restrict__ n1,
                                          const int* __restrict__ n2,
                                          u16* sA0, u16* sA1, u16* sBL, unsigned char* sZ,
                                          int m0, int t, int lane, int w, int wr, int wc,
                                          int2 (&icur)[5], unsigned& pmask, int& pcnt,
                                          uint4 (&gv)[5], f32x4 (&acc)[2][4]) {
    u16* sAcur = (S & 1) ? sA1 : sA0;
    u16* sAnxt = (S & 1) ? sA0 : sA1;
    const int rowoff = (lane >> 4) & 1;   // this lane's row within the step pair
    const int ehalf = lane >> 5;          // 0: even neighbors, 1: odd neighbors
    // 1. B(S) [4 gloads]
    stageBl(WT, sBL, S * 64, t);
    __builtin_amdgcn_sched_barrier(0);
    // 2. A(S+1) [1 gload]
    if (S < 3) stageA(Zl, sAnxt, m0, (S + 1) * 64, t);
    __builtin_amdgcn_sched_barrier(0);
    // 3. idx(S+1) [5 dwordx2]
    int2 inxt[5];
    if (S < 3) {
        int g = m0 + w * 8 + (S + 1) * 2 + rowoff;
        if (g >= MTOT) g = MTOT - 1;
        int p = (g >= NNODE);
        const int* nb = (p ? n2 : n1) + (size_t)(g - p * NNODE) * KNB;
        #pragma unroll
        for (int q = 0; q < 5; ++q) inxt[q] = *(const int2*)(nb + 2 * q);
    }
    __builtin_amdgcn_sched_barrier(0);
    // 4. consume G(S-1) (auto-wait leaves this step's issues in flight)
    if (S > 0) consume(gv, pmask, pcnt, w, lane, S - 1, sZ);
    __builtin_amdgcn_sched_barrier(0);
    // 5. issue G(S) [5 dwordx4]: lane covers 16B of its row; half-neighbors each
    {
        int g = m0 + w * 8 + S * 2 + rowoff;
        if (g >= MTOT) g = MTOT - 1;
        int p = (g >= NNODE);
        const unsigned char* zb = Z8 + (size_t)p * ((size_t)NNODE * 256) + ((lane & 15) << 4);
        unsigned mask = 0;
        int cnt = 0;
        #pragma unroll
        for (int q = 0; q < 5; ++q) {
            int ix = ehalf ? icur[q].y : icur[q].x;
            int valid = (ix > -1) ? 1 : 0;
            mask |= (unsigned)valid << q;
            cnt += valid;
            gv[q] = *(const uint4*)(zb + (size_t)(valid ? ix : 0) * 256);
        }
        pmask = mask;
        pcnt = cnt;
    }
    if (S < 3) {
        #pragma unroll
        for (int q = 0; q < 5; ++q) icur[q] = inxt[q];
    }
    __builtin_amdgcn_sched_barrier(0);
    // 6. counted wait: keep {A(S+1)1, idx5, G5}=11 (S<3) / {G5} (S=3); drains B(S)
    if (S < 3) asm volatile("s_waitcnt vmcnt(11)" ::: "memory");
    else       asm volatile("s_waitcnt vmcnt(5)" ::: "memory");
    __builtin_amdgcn_s_barrier();
    __builtin_amdgcn_s_setprio(1);
    mfma_left(sAcur, sBL, lane, wr, wc, acc);
    __builtin_amdgcn_s_setprio(0);
    __builtin_amdgcn_s_barrier();   // trailing barrier: protects sBL reuse (load-bearing!)
}

// ---- kernel 2: FUSED gather + GEMM. BM=64, BN=256. 64KB LDS -> 2 blocks/CU.
// 512 thr = 8 waves (2M x 4N), wave tile 32x64 -> acc[2][4] (32 regs).
// Left: 4 steps BK=64 bf16 (A dbuf, B single). Right: 4 steps BK=64 fp8 (B dbuf in sB).
// Gather: 5 uint4/step (16 lanes/row, even/odd-neighbor halves merged via shfl).
__global__ __launch_bounds__(512, 4) void gemm_fused(const u16* __restrict__ Zl,
                                                     const unsigned char* __restrict__ Z8,
                                                     const u16* __restrict__ WT,
                                                     const unsigned char* __restrict__ WT8,
                                                     const int* __restrict__ n1,
                                                     const int* __restrict__ n2,
                                                     float* __restrict__ C) {
    __shared__ char smem[65536];
    u16* sA0 = (u16*)smem;                               //  8 KB
    u16* sA1 = (u16*)(smem + 8192);                      //  8 KB
    u16* sBL = (u16*)(smem + 16384);                     // 32 KB (left B)
    unsigned char* sBr0 = (unsigned char*)(smem + 16384);// right chunk 0 (16 KB)
    unsigned char* sBr1 = (unsigned char*)(smem + 32768);// right chunk 1 (16 KB)
    unsigned char* sZ = (unsigned char*)(smem + 49152);  // 16 KB fp8 Zavg

    const int m0 = blockIdx.x * 64;
    const int t = threadIdx.x;
    const int lane = t & 63;
    const int w = t >> 6;
    const int wr = w >> 2, wc = w & 3;

    f32x4 acc[2][4] = {};
    uint4 gv[5];
    int2 icur[5];
    unsigned pmask = 0;
    int pcnt = 0;

    // prologue: A(0) + idx(0)
    stageA(Zl, sA0, m0, 0, t);
    {
        int g = m0 + w * 8 + ((lane >> 4) & 1);
        if (g >= MTOT) g = MTOT - 1;
        int p = (g >= NNODE);
        const int* nb = (p ? n2 : n1) + (size_t)(g - p * NNODE) * KNB;
        #pragma unroll
        for (int q = 0; q < 5; ++q) icur[q] = *(const int2*)(nb + 2 * q);
    }

    left_step<0>(Zl, WT, Z8, n1, n2, sA0, sA1, sBL, sZ, m0, t, lane, w, wr, wc, icur, pmask, pcnt, gv, acc);
    left_step<1>(Zl, WT, Z8, n1, n2, sA0, sA1, sBL, sZ, m0, t, lane, w, wr, wc, icur, pmask, pcnt, gv, acc);
    left_step<2>(Zl, WT, Z8, n1, n2, sA0, sA1, sBL, sZ, m0, t, lane, w, wr, wc, icur, pmask, pcnt, gv, acc);
    left_step<3>(Zl, WT, Z8, n1, n2, sA0, sA1, sBL, sZ, m0, t, lane, w, wr, wc, icur, pmask, pcnt, gv, acc);

    // right entry: final consume, stage chunk 0, full drain, sync
    consume(gv, pmask, pcnt, w, lane, 3, sZ);
    stageBr(WT8, sBr0, 0, t);
    asm volatile("s_waitcnt vmcnt(0)" ::: "memory");
    asm volatile("s_waitcnt lgkmcnt(0)" ::: "memory");
    __builtin_amdgcn_s_barrier();

#define RSTEP(R)                                                            \
    do {                                                                    \
        if ((R) < 3) {                                                      \
            stageBr(WT8, ((R) & 1) ? sBr0 : sBr1, ((R) + 1) * 64, t);       \
            asm volatile("s_waitcnt vmcnt(2)" ::: "memory");                \
        } else {                                                            \
            asm volatile("s_waitcnt vmcnt(0)" ::: "memory");                \
        }                                                                   \
        __builtin_amdgcn_s_barrier();                                       \
        __builtin_amdgcn_s_setprio(1);                                      \
        mfma_right(sZ, ((R) & 1) ? sBr1 : sBr0, (R), lane, wr, wc, acc);    \
        __builtin_amdgcn_s_setprio(0);                                      \
        if ((R) < 3) __builtin_amdgcn_s_barrier();                          \
    } while (0)

    RSTEP(0);
    RSTEP(1);
    RSTEP(2);
    RSTEP(3);
#undef RSTEP

    // epilogue: relu + store (C/D layout: col = lane&15, row = (lane>>4)*4 + q)
    const int l15 = lane & 15;
    const int hi = lane >> 4;
    #pragma unroll
    for (int i = 0; i < 2; ++i) {
        int rbase = m0 + wr * 32 + i * 16 + (hi << 2);
        #pragma unroll
        for (int j = 0; j < 4; ++j) {
            int col = wc * 64 + j * 16 + l15;
            #pragma unroll
            for (int q = 0; q < 4; ++q) {
                int row = rbase + q;
                if (row < MTOT) C[(size_t)row * NF + col] = fmaxf(acc[i][j][q], 0.f);
            }
        }
    }
}

extern "C" void kernel_launch(void* const* d_in, const int* in_sizes, int n_in,
                              void* d_out, int out_size, void* d_ws, size_t ws_size,
                              hipStream_t stream) {
    const float* Z1  = (const float*)d_in[0];
    const float* Z2  = (const float*)d_in[1];
    const float* Wr  = (const float*)d_in[2];
    const float* Wnr = (const float*)d_in[3];
    const int*   n1  = (const int*)d_in[4];
    const int*   n2  = (const int*)d_in[5];
    float* out = (float*)d_out;

    u16* WT            = (u16*)d_ws;                              // 128 KB
    unsigned char* WT8 = (unsigned char*)d_ws + 131072;           // 64 KB
    u16* Zleft         = (u16*)((unsigned char*)d_ws + 196608);   // 51.2 MB
    unsigned char* Z8  = (unsigned char*)d_ws + 196608 + (size_t)MTOT * 512;  // 25.6 MB

    cast_all<<<13012, 256, 0, stream>>>(Z1, Z2, Wr, Wnr, Zleft, Z8, WT, WT8);
    gemm_fused<<<1563, 512, 0, stream>>>(Zleft, Z8, WT, WT8, n1, n2, out);
}

// Round 16
// 109.057 us; speedup vs baseline: 1.1178x; 1.1178x over previous
//
#include <hip/hip_runtime.h>
#include <hip/hip_bf16.h>
#include <hip/hip_fp8.h>

#define NNODE 50000
#define MTOT  100000   // 2*NNODE rows
#define NF    256
#define KNB   10

typedef unsigned short u16;
typedef float f32x4 __attribute__((ext_vector_type(4)));
typedef float f32x2 __attribute__((ext_vector_type(2)));
typedef short bf16x8 __attribute__((ext_vector_type(8)));

__device__ __forceinline__ u16 f2bf(float f) {
    unsigned u = __builtin_bit_cast(unsigned, f);
    unsigned r = (u + 0x7fffu + ((u >> 16) & 1u)) >> 16;
    return (u16)r;
}
__device__ __forceinline__ unsigned char f2f8(float f) {
    return (unsigned char)__hip_fp8_e4m3(f).__x;
}
__device__ __forceinline__ float f8tof(unsigned char b) {
    __hip_fp8_e4m3 h;
    h.__x = (__hip_fp8_storage_t)b;
    return (float)h;
}
template <int WORD>
__device__ __forceinline__ f32x2 cvt2_fp8(unsigned v) {
#if __has_builtin(__builtin_amdgcn_cvt_pk_f32_fp8)
    auto c = __builtin_amdgcn_cvt_pk_f32_fp8((int)v, WORD);
    f32x2 r; r.x = c[0]; r.y = c[1];
    return r;
#else
    unsigned s = WORD ? (v >> 16) : v;
    f32x2 r;
    r.x = f8tof((unsigned char)(s & 0xff));
    r.y = f8tof((unsigned char)((s >> 8) & 0xff));
    return r;
#endif
}
template <int WORD>
__device__ __forceinline__ unsigned pk_fp8(float a, float b, unsigned old) {
#if __has_builtin(__builtin_amdgcn_cvt_pk_fp8_f32)
    return (unsigned)__builtin_amdgcn_cvt_pk_fp8_f32(a, b, (int)old, WORD);
#else
    unsigned lo = (unsigned)f2f8(a) | ((unsigned)f2f8(b) << 8);
    return WORD ? ((old & 0x0000ffffu) | (lo << 16)) : ((old & 0xffff0000u) | lo);
#endif
}
__device__ __forceinline__ void gload_lds16(const void* g, void* l) {
    __builtin_amdgcn_global_load_lds(
        (const __attribute__((address_space(1))) unsigned int*)g,
        (__attribute__((address_space(3))) unsigned int*)l, 16, 0, 0);
}

// ---- kernel 1: merged cast.
//  [0,12500): Z -> bf16 Zleft + fp8 Z8
//  [12500,12756): WT bf16 [256 n][256 k] = Wr^T
//  [12756,13012): WT8 fp8 [256 n][256 k] = Wnr^T, 8B-halves of each 16B swapped
//                 when (n>>2)&1 (bank-spread bake for the right-B LDS reads)
__global__ __launch_bounds__(256) void cast_all(const float* __restrict__ Z1,
                                                const float* __restrict__ Z2,
                                                const float* __restrict__ Wr,
                                                const float* __restrict__ Wnr,
                                                u16* __restrict__ Zleft,
                                                unsigned char* __restrict__ Z8,
                                                u16* __restrict__ WT,
                                                unsigned char* __restrict__ WT8) {
    int b = blockIdx.x;
    if (b < 12500) {
        unsigned id = b * 256 + threadIdx.x;
        int m = id >> 5;
        int d = (id & 31) << 3;
        const float* src = (m < NNODE) ? (Z1 + (size_t)m * 256 + d)
                                       : (Z2 + (size_t)(m - NNODE) * 256 + d);
        float4 a = *(const float4*)src;
        float4 bb = *(const float4*)(src + 4);
        uint4 o;
        o.x = (unsigned)f2bf(a.x) | ((unsigned)f2bf(a.y) << 16);
        o.y = (unsigned)f2bf(a.z) | ((unsigned)f2bf(a.w) << 16);
        o.z = (unsigned)f2bf(bb.x) | ((unsigned)f2bf(bb.y) << 16);
        o.w = (unsigned)f2bf(bb.z) | ((unsigned)f2bf(bb.w) << 16);
        *(uint4*)(Zleft + (size_t)m * 256 + d) = o;
        uint2 o8;
        o8.x = (unsigned)f2f8(a.x) | ((unsigned)f2f8(a.y) << 8) |
               ((unsigned)f2f8(a.z) << 16) | ((unsigned)f2f8(a.w) << 24);
        o8.y = (unsigned)f2f8(bb.x) | ((unsigned)f2f8(bb.y) << 8) |
               ((unsigned)f2f8(bb.z) << 16) | ((unsigned)f2f8(bb.w) << 24);
        *(uint2*)(Z8 + (size_t)m * 256 + d) = o8;
    } else if (b < 12756) {
        int id = (b - 12500) * 256 + threadIdx.x;
        int n = id >> 8, k = id & 255;
        WT[n * 256 + k] = f2bf(Wr[(size_t)k * 256 + n]);
    } else {
        int id = (b - 12756) * 256 + threadIdx.x;
        int n = id >> 8, k = id & 255;
        int kb = k ^ (((n >> 2) & 1) << 3);          // bake: swap 8B halves per 16B
        WT8[n * 256 + kb] = f2f8(Wnr[(size_t)k * 256 + n]);
    }
}

// ---- staging: linear LDS dest + inverse-swizzled global source (16B granules)
__device__ __forceinline__ void stageA(const u16* __restrict__ Zl, u16* dst,
                                       int m0, int kt, int t) {
    // [64r][64k] bf16 = 512 granules, 1/thread, XOR row&7 (8 granules/row)
    int row = t >> 3, gd = t & 7;
    int gs = gd ^ (row & 7);
    int grow = m0 + row;
    if (grow >= MTOT) grow = MTOT - 1;
    gload_lds16(Zl + (size_t)grow * 256 + kt + gs * 8, dst + t * 8);
}
__device__ __forceinline__ void stageBl(const u16* __restrict__ WT, u16* dst,
                                        int kt, int t) {
    // [256c][64k] bf16 = 2048 granules, 4/thread, XOR col&7
    #pragma unroll
    for (int rp = 0; rp < 4; ++rp) {
        int c = rp * 512 + t;
        int col = c >> 3, gd = c & 7;
        int gs = gd ^ (col & 7);
        gload_lds16(WT + (size_t)col * 256 + kt + gs * 8, dst + c * 8);
    }
}
__device__ __forceinline__ void stageBr(const unsigned char* __restrict__ WT8,
                                        unsigned char* dst, int ktr, int t) {
    // [256c][64k] fp8 = 1024 granules, 2/thread, XOR col&3 (half-bake in data)
    #pragma unroll
    for (int rp = 0; rp < 2; ++rp) {
        int c = rp * 512 + t;
        int col = c >> 2, gd = c & 3;
        int gs = gd ^ (col & 3);
        gload_lds16(WT8 + (size_t)col * 256 + ktr + gs * 16, dst + c * 16);
    }
}

__device__ __forceinline__ void mfma_left(const u16* sAc, const u16* sBc, int lane,
                                          int wr, int wc, f32x4 (&acc)[2][4]) {
    const int hi = lane >> 4, l15 = lane & 15;
    #pragma unroll
    for (int kk = 0; kk < 64; kk += 32) {
        int g = (kk >> 3) + hi;                     // granule 0..7
        bf16x8 af[2], bfr[4];
        #pragma unroll
        for (int i = 0; i < 2; ++i) {
            int row = wr * 32 + i * 16 + l15;
            af[i] = *(const bf16x8*)((const char*)sAc + row * 128 + ((g ^ (row & 7)) << 4));
        }
        #pragma unroll
        for (int j = 0; j < 4; ++j) {
            int col = wc * 64 + j * 16 + l15;
            bfr[j] = *(const bf16x8*)((const char*)sBc + col * 128 + ((g ^ (col & 7)) << 4));
        }
        #pragma unroll
        for (int i = 0; i < 2; ++i)
            #pragma unroll
            for (int j = 0; j < 4; ++j)
                acc[i][j] = __builtin_amdgcn_mfma_f32_16x16x32_bf16(af[i], bfr[j], acc[i][j], 0, 0, 0);
    }
}
__device__ __forceinline__ void mfma_right(const unsigned char* sZ, const unsigned char* sBc,
                                           int R, int lane, int wr, int wc,
                                           f32x4 (&acc)[2][4]) {
    const int hi = lane >> 4, l15 = lane & 15;
    #pragma unroll
    for (int m = 0; m < 2; ++m) {
        long long az[2], bz[4];
        #pragma unroll
        for (int i = 0; i < 2; ++i) {
            int row = wr * 32 + i * 16 + l15;
            int g8 = R * 8 + m * 4 + hi;            // 8B granule 0..31
            az[i] = *(const long long*)(sZ + row * 256 + ((g8 ^ (row & 7)) << 3));
        }
        #pragma unroll
        for (int j = 0; j < 4; ++j) {
            int col = wc * 64 + j * 16 + l15;
            int G = 2 * m + (hi >> 1);              // 16B granule 0..3
            int hb = ((hi & 1) ^ ((col >> 2) & 1)) << 3;   // un-bake half select
            bz[j] = *(const long long*)(sBc + col * 64 + ((G ^ (col & 3)) << 4) + hb);
        }
        #pragma unroll
        for (int i = 0; i < 2; ++i)
            #pragma unroll
            for (int j = 0; j < 4; ++j)
                acc[i][j] = __builtin_amdgcn_mfma_f32_16x16x32_fp8_fp8(az[i], bz[j], acc[i][j], 0, 0, 0);
    }
}

// ---- consume gather packet of step s: average -> fp8 -> swizzled sZ write
__device__ __forceinline__ void consume(const uint2 (&gv)[KNB], unsigned mask, int cnt,
                                        int w, int lane, int s, unsigned char* sZ) {
    f32x2 a0 = {0.f, 0.f}, a1 = {0.f, 0.f}, a2 = {0.f, 0.f}, a3 = {0.f, 0.f};
    #pragma unroll
    for (int k = 0; k < KNB; ++k) {
        float mm = (float)((mask >> k) & 1u);
        f32x2 m2 = {mm, mm};
        a0 += m2 * cvt2_fp8<0>(gv[k].x);
        a1 += m2 * cvt2_fp8<1>(gv[k].x);
        a2 += m2 * cvt2_fp8<0>(gv[k].y);
        a3 += m2 * cvt2_fp8<1>(gv[k].y);
    }
    float sc = 1.0f / (float)(cnt > 0 ? cnt : 1);
    unsigned w0 = pk_fp8<0>(a0.x * sc, a0.y * sc, 0u);
    w0 = pk_fp8<1>(a1.x * sc, a1.y * sc, w0);
    unsigned w1 = pk_fp8<0>(a2.x * sc, a2.y * sc, 0u);
    w1 = pk_fp8<1>(a3.x * sc, a3.y * sc, w1);
    int rl = w * 8 + s * 2 + (lane >> 5);           // local row 0..63
    int gp = (lane & 31) ^ (rl & 7);
    *(uint2*)(sZ + rl * 256 + (gp << 3)) = make_uint2(w0, w1);
}

// ---- left step S (0..3): pinned issue order + counted vmcnt.
// TWO barriers per step, both load-bearing: the pre-MFMA barrier publishes the
// staged B(S)/A tiles; the TRAILING barrier keeps any wave from staging B(S+1)
// over the single sBL buffer while another wave still MFMA-reads B(S).
// (R13 dropped the trailing barrier -> absmax 36 data race. Do not remove.)
template <int S>
__device__ __forceinline__ void left_step(const u16* __restrict__ Zl,
                                          const u16* __restrict__ WT,
                                          const unsigned char* __restrict__ Z8,
                                          const int* __restrict__ n1,
                                          const int* __restrict__ n2,
                                          u16* sA0, u16* sA1, u16* sBL, unsigned char* sZ,
                                          int m0, int t, int lane, int w, int wr, int wc,
                                          int2 (&icur)[5], unsigned& pmask, int& pcnt,
                                          uint2 (&gv)[KNB], f32x4 (&acc)[2][4]) {
    u16* sAcur = (S & 1) ? sA1 : sA0;
    u16* sAnxt = (S & 1) ? sA0 : sA1;
    // 1. B(S) [4 gloads]
    stageBl(WT, sBL, S * 64, t);
    __builtin_amdgcn_sched_barrier(0);
    // 2. A(S+1) [1 gload]
    if (S < 3) stageA(Zl, sAnxt, m0, (S + 1) * 64, t);
    __builtin_amdgcn_sched_barrier(0);
    // 3. idx(S+1) [5 dwordx2]
    int2 inxt[5];
    if (S < 3) {
        int rl = w * 8 + (S + 1) * 2 + (lane >> 5);
        int g = m0 + rl;
        if (g >= MTOT) g = MTOT - 1;
        int p = (g >= NNODE);
        const int* nb = (p ? n2 : n1) + (size_t)(g - p * NNODE) * KNB;
        #pragma unroll
        for (int q = 0; q < 5; ++q) inxt[q] = *(const int2*)(nb + 2 * q);
    }
    __builtin_amdgcn_sched_barrier(0);
    // 4. consume G(S-1) (auto-wait leaves this step's issues in flight)
    if (S > 0) consume(gv, pmask, pcnt, w, lane, S - 1, sZ);
    __builtin_amdgcn_sched_barrier(0);
    // 5. issue G(S) [10 dwordx2] using icur; derive mask/cnt; rotate idx
    {
        int g = m0 + w * 8 + S * 2 + (lane >> 5);
        if (g >= MTOT) g = MTOT - 1;
        int p = (g >= NNODE);
        const unsigned char* zb = Z8 + (size_t)p * ((size_t)NNODE * 256) + ((lane & 31) << 3);
        unsigned mask = 0;
        int cnt = 0;
        #pragma unroll
        for (int k = 0; k < KNB; ++k) {
            int ix = (k & 1) ? icur[k >> 1].y : icur[k >> 1].x;
            int valid = (ix > -1) ? 1 : 0;
            mask |= (unsigned)valid << k;
            cnt += valid;
            gv[k] = *(const uint2*)(zb + (size_t)(valid ? ix : 0) * 256);
        }
        pmask = mask;
        pcnt = cnt;
    }
    if (S < 3) {
        #pragma unroll
        for (int q = 0; q < 5; ++q) icur[q] = inxt[q];
    }
    __builtin_amdgcn_sched_barrier(0);
    // 6. counted wait: keep {A(S+1)1, idx5, G10}=16 (S<3) / {G10} (S=3); drains B(S)
    if (S < 3) asm volatile("s_waitcnt vmcnt(16)" ::: "memory");
    else       asm volatile("s_waitcnt vmcnt(10)" ::: "memory");
    __builtin_amdgcn_s_barrier();
    __builtin_amdgcn_s_setprio(1);
    mfma_left(sAcur, sBL, lane, wr, wc, acc);
    __builtin_amdgcn_s_setprio(0);
    __builtin_amdgcn_s_barrier();   // trailing barrier: protects sBL reuse (load-bearing!)
}

// ---- kernel 2: FUSED gather + GEMM. BM=64, BN=256. 64KB LDS -> 2 blocks/CU.
// 512 thr = 8 waves (2M x 4N), wave tile 32x64 -> acc[2][4] (32 regs).
// Left: 4 steps BK=64 bf16 (A dbuf, B single). Right: 4 steps BK=64 fp8 (B dbuf in sB).
__global__ __launch_bounds__(512, 4) void gemm_fused(const u16* __restrict__ Zl,
                                                     const unsigned char* __restrict__ Z8,
                                                     const u16* __restrict__ WT,
                                                     const unsigned char* __restrict__ WT8,
                                                     const int* __restrict__ n1,
                                                     const int* __restrict__ n2,
                                                     float* __restrict__ C) {
    __shared__ char smem[65536];
    u16* sA0 = (u16*)smem;                               //  8 KB
    u16* sA1 = (u16*)(smem + 8192);                      //  8 KB
    u16* sBL = (u16*)(smem + 16384);                     // 32 KB (left B)
    unsigned char* sBr0 = (unsigned char*)(smem + 16384);// right chunk 0 (16 KB)
    unsigned char* sBr1 = (unsigned char*)(smem + 32768);// right chunk 1 (16 KB)
    unsigned char* sZ = (unsigned char*)(smem + 49152);  // 16 KB fp8 Zavg

    const int m0 = blockIdx.x * 64;
    const int t = threadIdx.x;
    const int lane = t & 63;
    const int w = t >> 6;
    const int wr = w >> 2, wc = w & 3;

    f32x4 acc[2][4] = {};
    uint2 gv[KNB];
    int2 icur[5];
    unsigned pmask = 0;
    int pcnt = 0;

    // prologue: A(0) + idx(0)
    stageA(Zl, sA0, m0, 0, t);
    {
        int g = m0 + w * 8 + (lane >> 5);
        if (g >= MTOT) g = MTOT - 1;
        int p = (g >= NNODE);
        const int* nb = (p ? n2 : n1) + (size_t)(g - p * NNODE) * KNB;
        #pragma unroll
        for (int q = 0; q < 5; ++q) icur[q] = *(const int2*)(nb + 2 * q);
    }

    left_step<0>(Zl, WT, Z8, n1, n2, sA0, sA1, sBL, sZ, m0, t, lane, w, wr, wc, icur, pmask, pcnt, gv, acc);
    left_step<1>(Zl, WT, Z8, n1, n2, sA0, sA1, sBL, sZ, m0, t, lane, w, wr, wc, icur, pmask, pcnt, gv, acc);
    left_step<2>(Zl, WT, Z8, n1, n2, sA0, sA1, sBL, sZ, m0, t, lane, w, wr, wc, icur, pmask, pcnt, gv, acc);
    left_step<3>(Zl, WT, Z8, n1, n2, sA0, sA1, sBL, sZ, m0, t, lane, w, wr, wc, icur, pmask, pcnt, gv, acc);

    // right entry: final consume, stage chunk 0, full drain, sync
    consume(gv, pmask, pcnt, w, lane, 3, sZ);
    stageBr(WT8, sBr0, 0, t);
    asm volatile("s_waitcnt vmcnt(0)" ::: "memory");
    asm volatile("s_waitcnt lgkmcnt(0)" ::: "memory");
    __builtin_amdgcn_s_barrier();

#define RSTEP(R)                                                            \
    do {                                                                    \
        if ((R) < 3) {                                                      \
            stageBr(WT8, ((R) & 1) ? sBr0 : sBr1, ((R) + 1) * 64, t);       \
            asm volatile("s_waitcnt vmcnt(2)" ::: "memory");                \
        } else {                                                            \
            asm volatile("s_waitcnt vmcnt(0)" ::: "memory");                \
        }                                                                   \
        __builtin_amdgcn_s_barrier();                                       \
        __builtin_amdgcn_s_setprio(1);                                      \
        mfma_right(sZ, ((R) & 1) ? sBr1 : sBr0, (R), lane, wr, wc, acc);    \
        __builtin_amdgcn_s_setprio(0);                                      \
        if ((R) < 3) __builtin_amdgcn_s_barrier();                          \
    } while (0)

    RSTEP(0);
    RSTEP(1);
    RSTEP(2);
    RSTEP(3);
#undef RSTEP

    // epilogue: relu + store (C/D layout: col = lane&15, row = (lane>>4)*4 + q)
    const int l15 = lane & 15;
    const int hi = lane >> 4;
    #pragma unroll
    for (int i = 0; i < 2; ++i) {
        int rbase = m0 + wr * 32 + i * 16 + (hi << 2);
        #pragma unroll
        for (int j = 0; j < 4; ++j) {
            int col = wc * 64 + j * 16 + l15;
            #pragma unroll
            for (int q = 0; q < 4; ++q) {
                int row = rbase + q;
                if (row < MTOT) C[(size_t)row * NF + col] = fmaxf(acc[i][j][q], 0.f);
            }
        }
    }
}

extern "C" void kernel_launch(void* const* d_in, const int* in_sizes, int n_in,
                              void* d_out, int out_size, void* d_ws, size_t ws_size,
                              hipStream_t stream) {
    const float* Z1  = (const float*)d_in[0];
    const float* Z2  = (const float*)d_in[1];
    const float* Wr  = (const float*)d_in[2];
    const float* Wnr = (const float*)d_in[3];
    const int*   n1  = (const int*)d_in[4];
    const int*   n2  = (const int*)d_in[5];
    float* out = (float*)d_out;

    u16* WT            = (u16*)d_ws;                              // 128 KB
    unsigned char* WT8 = (unsigned char*)d_ws + 131072;           // 64 KB
    u16* Zleft         = (u16*)((unsigned char*)d_ws + 196608);   // 51.2 MB
    unsigned char* Z8  = (unsigned char*)d_ws + 196608 + (size_t)MTOT * 512;  // 25.6 MB

    cast_all<<<13012, 256, 0, stream>>>(Z1, Z2, Wr, Wnr, Zleft, Z8, WT, WT8);
    gemm_fused<<<1563, 512, 0, stream>>>(Zleft, Z8, WT, WT8, n1, n2, out);
}